// Round 1
// baseline (331.199 us; speedup 1.0000x reference)
//
#include <hip/hip_runtime.h>
#include <hip/hip_bf16.h>
#include <stdint.h>

// ---------------------------------------------------------------------------
// Single-head self-attention, B=4, S=2048, D=1024, fp32 in/out.
// Pipeline (all matmuls bf16 MFMA 16x16x32, m97-style 128x128 tiles):
//   1. xb   = bf16(x)                         [8192,1024]
//   2. wt   = bf16(W^T) for q,k,v             [3][1024,1024]  (n-major)
//   3. qkv  = xb @ wt^T + bias   (gemm_bt z=0..2, bf16 out)
//   4. vT   = transpose(v) per batch          [4][1024,2048]
//   5. sc   = (q @ k^T) * 1/32   (gemm_bt per batch, fp32 out) [4][2048,2048]
//   6. P    = softmax rows of sc, bf16, written in place (row pitch 4096 bf16)
//   7. out  = P @ vT^T           (gemm_bt per batch, fp32 -> d_out)
// Workspace: xb 16MB | wt 6MB | qkv 48MB | scores 64MB  (vT reuses xb) = 134MB
// ---------------------------------------------------------------------------

typedef __attribute__((ext_vector_type(8))) short short8;   // 8 bf16 = 4 VGPR
typedef __attribute__((ext_vector_type(4))) float f32x4;    // MFMA C/D

__device__ __forceinline__ unsigned short f2bf(float f) {
  union { float f; uint32_t u; } c; c.f = f;
  uint32_t u = c.u;
  u += 0x7FFFu + ((u >> 16) & 1u);   // RNE
  return (unsigned short)(u >> 16);
}

// async global->LDS, 16B per lane. LDS dest is wave-uniform base + lane*16:
// our lds ptr is base + tid*16 with global addr for exactly that chunk.
__device__ __forceinline__ void gl16(const void* g, void* l) {
  __builtin_amdgcn_global_load_lds(
      (const __attribute__((address_space(1))) unsigned int*)g,
      (__attribute__((address_space(3))) unsigned int*)l, 16, 0, 0);
}

// C = A @ B^T. A: [M,K] row-major bf16 (lda), B: [N,K] row-major bf16 (ldb).
// EPI 0: C bf16, += bias[col] (bias selected by z). EPI 1: C fp32, *= scale.
// Grid: (N/128, M/128, Z). Block 256 (4 waves, 2x2, each 64x64 = 4x4 frags).
template <int EPI>
__global__ __launch_bounds__(256) void gemm_bt(
    const short* __restrict__ A, int lda, long sAz,
    const short* __restrict__ B, int ldb, long sBz,
    void* __restrict__ Cv, int ldc, long sCz,
    int K, float scale,
    const float* __restrict__ bias0, const float* __restrict__ bias1,
    const float* __restrict__ bias2)
{
  __shared__ short sA[128 * 32];
  __shared__ short sB[128 * 32];
  const int tid  = threadIdx.x;
  const int lane = tid & 63;
  const int wid  = tid >> 6;
  const int z    = blockIdx.z;
  const long tileM = (long)blockIdx.y * 128;
  const long tileN = (long)blockIdx.x * 128;
  const short* Az = A + (long)z * sAz;
  const short* Bz = B + (long)z * sBz;

  // staging: 512 chunks of 16B per tile (128 rows x 32 cols bf16), 2 per thread
  const int c0 = tid, c1 = 256 + tid;
  const short* ga0 = Az + (tileM + (c0 >> 2)) * lda + (c0 & 3) * 8;
  const short* ga1 = Az + (tileM + (c1 >> 2)) * lda + (c1 & 3) * 8;
  const short* gb0 = Bz + (tileN + (c0 >> 2)) * ldb + (c0 & 3) * 8;
  const short* gb1 = Bz + (tileN + (c1 >> 2)) * ldb + (c1 & 3) * 8;
  short* la0 = &sA[c0 * 8]; short* la1 = &sA[c1 * 8];
  short* lb0 = &sB[c0 * 8]; short* lb1 = &sB[c1 * 8];

  const int fr = lane & 15, quad = lane >> 4;
  const int waveM = (wid >> 1) * 64, waveN = (wid & 1) * 64;

  f32x4 acc[4][4] = {};

  for (int kt = 0; kt < K; kt += 32) {
    __syncthreads();                 // prior readers done before overwrite
    gl16(ga0 + kt, la0);
    gl16(ga1 + kt, la1);
    gl16(gb0 + kt, lb0);
    gl16(gb1 + kt, lb1);
    __syncthreads();                 // drains vmcnt (loads landed in LDS)

    short8 af[4], bf[4];
#pragma unroll
    for (int i = 0; i < 4; ++i)
      af[i] = *(const short8*)&sA[(waveM + i * 16 + fr) * 32 + quad * 8];
#pragma unroll
    for (int j = 0; j < 4; ++j)
      bf[j] = *(const short8*)&sB[(waveN + j * 16 + fr) * 32 + quad * 8];
#pragma unroll
    for (int i = 0; i < 4; ++i)
#pragma unroll
      for (int j = 0; j < 4; ++j)
        acc[i][j] = __builtin_amdgcn_mfma_f32_16x16x32_bf16(af[i], bf[j],
                                                            acc[i][j], 0, 0, 0);
  }

  // epilogue: D[row=(lane>>4)*4+r][col=lane&15] (m89/m91-verified layout)
  const int rbase = quad * 4;
  if (EPI == 0) {
    short* C = (short*)Cv + (long)z * sCz;
    const float* bias = (z == 0) ? bias0 : ((z == 1) ? bias1 : bias2);
#pragma unroll
    for (int j = 0; j < 4; ++j) {
      const long gc = tileN + waveN + j * 16 + fr;
      const float bv = bias[gc];
#pragma unroll
      for (int i = 0; i < 4; ++i) {
        const long gr = tileM + waveM + i * 16 + rbase;
#pragma unroll
        for (int r = 0; r < 4; ++r)
          C[(gr + r) * ldc + gc] = (short)f2bf(acc[i][j][r] + bv);
      }
    }
  } else {
    float* C = (float*)Cv + (long)z * sCz;
#pragma unroll
    for (int j = 0; j < 4; ++j) {
      const long gc = tileN + waveN + j * 16 + fr;
#pragma unroll
      for (int i = 0; i < 4; ++i) {
        const long gr = tileM + waveM + i * 16 + rbase;
#pragma unroll
        for (int r = 0; r < 4; ++r)
          C[(gr + r) * ldc + gc] = acc[i][j][r] * scale;
      }
    }
  }
}

// fp32 -> bf16 elementwise, float4/ushort4 vectorized. n = 8192*1024.
__global__ __launch_bounds__(256) void cvt_f32_to_bf16(
    const float4* __restrict__ x, ushort4* __restrict__ y)
{
  const long i = (long)blockIdx.x * 256 + threadIdx.x;
  float4 v = x[i];
  ushort4 o;
  o.x = f2bf(v.x); o.y = f2bf(v.y); o.z = f2bf(v.z); o.w = f2bf(v.w);
  y[i] = o;
}

// W [1024,1024] fp32 (d-major) -> WT [1024,1024] bf16 (n-major), z selects q/k/v
__global__ __launch_bounds__(256) void transpose_cvt_w(
    const float* __restrict__ Wq, const float* __restrict__ Wk,
    const float* __restrict__ Wv, short* __restrict__ WT)
{
  __shared__ short tile[32][33];
  const int z = blockIdx.z;
  const float* W = (z == 0) ? Wq : ((z == 1) ? Wk : Wv);
  short* d = WT + (long)z * 1024 * 1024;
  const int n0 = blockIdx.x * 32, d0 = blockIdx.y * 32;
  const int tx = threadIdx.x & 31, ty = threadIdx.x >> 5;
#pragma unroll
  for (int p = 0; p < 4; ++p)
    tile[ty + p * 8][tx] = (short)f2bf(W[(long)(d0 + ty + p * 8) * 1024 + n0 + tx]);
  __syncthreads();
#pragma unroll
  for (int p = 0; p < 4; ++p)
    d[(long)(n0 + ty + p * 8) * 1024 + d0 + tx] = tile[tx][ty + p * 8];
}

// v [4][2048][1024] bf16 -> vT [4][1024][2048] bf16
__global__ __launch_bounds__(256) void transpose_bf16(
    const short* __restrict__ src, short* __restrict__ dst)
{
  __shared__ short tile[32][33];
  const int z = blockIdx.z;
  const int d0 = blockIdx.x * 32, t0 = blockIdx.y * 32;
  const int tx = threadIdx.x & 31, ty = threadIdx.x >> 5;
  const short* s = src + (long)z * 2048 * 1024;
  short* d = dst + (long)z * 1024 * 2048;
#pragma unroll
  for (int p = 0; p < 4; ++p)
    tile[ty + p * 8][tx] = s[(long)(t0 + ty + p * 8) * 1024 + d0 + tx];
  __syncthreads();
#pragma unroll
  for (int p = 0; p < 4; ++p)
    d[(long)(d0 + ty + p * 8) * 2048 + t0 + tx] = tile[tx][ty + p * 8];
}

// row softmax over 2048 fp32 scores -> 2048 bf16 probs written in place
// (row pitch stays 2048 floats = 4096 bf16). Grid 8192 rows, block 256.
__global__ __launch_bounds__(256) void softmax_rows(
    const float* __restrict__ S, short* __restrict__ P)
{
  const int row = blockIdx.x;
  const int tid = threadIdx.x;
  const float* s = S + (long)row * 2048;
  float4 v0 = ((const float4*)s)[tid * 2];
  float4 v1 = ((const float4*)s)[tid * 2 + 1];
  float vals[8] = {v0.x, v0.y, v0.z, v0.w, v1.x, v1.y, v1.z, v1.w};
  float m = vals[0];
#pragma unroll
  for (int i = 1; i < 8; ++i) m = fmaxf(m, vals[i]);
#pragma unroll
  for (int o = 32; o >= 1; o >>= 1) m = fmaxf(m, __shfl_xor(m, o));
  __shared__ float red[8];
  const int wid = tid >> 6, lane = tid & 63;
  if (lane == 0) red[wid] = m;
  __syncthreads();
  m = fmaxf(fmaxf(red[0], red[1]), fmaxf(red[2], red[3]));
  float sum = 0.f;
#pragma unroll
  for (int i = 0; i < 8; ++i) {
    vals[i] = exp2f((vals[i] - m) * 1.4426950408889634f);
    sum += vals[i];
  }
#pragma unroll
  for (int o = 32; o >= 1; o >>= 1) sum += __shfl_xor(sum, o);
  if (lane == 0) red[4 + wid] = sum;
  __syncthreads();
  sum = red[4] + red[5] + red[6] + red[7];
  const float rinv = 1.0f / sum;
  short8 o;
#pragma unroll
  for (int i = 0; i < 8; ++i) o[i] = (short)f2bf(vals[i] * rinv);
  *(short8*)(P + (long)row * 4096 + tid * 8) = o;
}

extern "C" void kernel_launch(void* const* d_in, const int* in_sizes, int n_in,
                              void* d_out, int out_size, void* d_ws, size_t ws_size,
                              hipStream_t stream) {
  const float* x  = (const float*)d_in[0];
  const float* Wq = (const float*)d_in[1];
  const float* bq = (const float*)d_in[2];
  const float* Wk = (const float*)d_in[3];
  const float* bk = (const float*)d_in[4];
  const float* Wv = (const float*)d_in[5];
  const float* bv = (const float*)d_in[6];

  char* ws = (char*)d_ws;
  short* xb  = (short*)(ws);                 // 16 MB, reused as vT after QKV gemm
  short* wt  = (short*)(ws + 16777216);      // 6 MB
  short* qkv = (short*)(ws + 23068672);      // 48 MB: q|k|v each [8192,1024]
  float* sc  = (float*)(ws + 73400320);      // 64 MB: [4][2048,2048]
  short* vT  = xb;                           // [4][1024,2048]

  // 1. x -> bf16
  cvt_f32_to_bf16<<<8192, 256, 0, stream>>>((const float4*)x, (ushort4*)xb);
  // 2. W^T -> bf16
  transpose_cvt_w<<<dim3(32, 32, 3), 256, 0, stream>>>(Wq, Wk, Wv, wt);
  // 3. q,k,v = x @ W + b   (bf16 out)
  gemm_bt<0><<<dim3(8, 64, 3), 256, 0, stream>>>(
      xb, 1024, 0L, wt, 1024, 1048576L, qkv, 1024, 8388608L,
      1024, 1.0f, bq, bk, bv);
  // 4. vT per batch
  transpose_bf16<<<dim3(32, 64, 4), 256, 0, stream>>>(qkv + 2L * 8388608, vT);
  // 5. scores = q @ k^T * 1/sqrt(D)  (fp32)
  gemm_bt<1><<<dim3(16, 16, 4), 256, 0, stream>>>(
      qkv, 1024, 2097152L, qkv + 8388608, 1024, 2097152L, sc, 2048, 4194304L,
      1024, 0.03125f, nullptr, nullptr, nullptr);
  // 6. P = softmax(scores), bf16 in place
  softmax_rows<<<8192, 256, 0, stream>>>(sc, (short*)sc);
  // 7. out = P @ v  (fp32 -> d_out)
  gemm_bt<1><<<dim3(8, 16, 4), 256, 0, stream>>>(
      (const short*)sc, 4096, 8388608L, vT, 2048, 2097152L, d_out, 1024, 2097152L,
      2048, 1.0f, nullptr, nullptr, nullptr);
}

// Round 2
// 299.202 us; speedup vs baseline: 1.1069x; 1.1069x over previous
//
#include <hip/hip_runtime.h>
#include <hip/hip_bf16.h>
#include <stdint.h>

// ---------------------------------------------------------------------------
// Single-head self-attention, B=4, S=2048, D=1024, fp32 in/out.
// Round 2: BK=64 (two 32-col LDS panels, gl16-compatible), softmax fused into
// scores-GEMM epilogue (exp2 + bf16 P' + atomic fp32 rowsum; PV normalizes),
// LDS-transpose vectorized bf16 epilogues (dwordx4 stores).
// Pipeline:
//   1. xb   = bf16(x)                          [8192,1024]
//   2. wt   = bf16(W^T) q,k,v                  [3][1024,1024]
//   3. qkv  = xb @ wt^T + bias    (EPI0, bf16) [3][8192,1024]
//   4. vT   = transpose(v) per batch           [4][1024,2048]
//   5. P'   = exp2(q@k^T * s*log2e) (EPI1, bf16) + rowsum atomics
//   6. out  = (P' @ vT^T) / rowsum (EPI2, fp32 -> d_out)
// ---------------------------------------------------------------------------

typedef __attribute__((ext_vector_type(8))) short short8;   // 8 bf16 = 4 VGPR
typedef __attribute__((ext_vector_type(4))) float f32x4;    // MFMA C/D

__device__ __forceinline__ unsigned short f2bf(float f) {
  union { float f; uint32_t u; } c; c.f = f;
  uint32_t u = c.u;
  u += 0x7FFFu + ((u >> 16) & 1u);   // RNE
  return (unsigned short)(u >> 16);
}

// async global->LDS, 16B/lane; LDS dest is wave-uniform base + lane*16.
__device__ __forceinline__ void gl16(const void* g, void* l) {
  __builtin_amdgcn_global_load_lds(
      (const __attribute__((address_space(1))) unsigned int*)g,
      (__attribute__((address_space(3))) unsigned int*)l, 16, 0, 0);
}

// C = A @ B^T. A: [M,K] bf16 (lda), B: [N,K] bf16 (ldb). BK=64.
// EPI 0: C bf16, += bias[col] (selected by z).
// EPI 1: C bf16 = exp2(acc*scale); fp32 rowsum atomics (softmax numerator).
// EPI 2: C fp32 = acc / rowsum[row].
// Grid (N/128, M/128, Z), block 256 = 4 waves (2x2 of 64x64).
template <int EPI>
__global__ __launch_bounds__(256) void gemm_bt(
    const short* __restrict__ A, int lda, long sAz,
    const short* __restrict__ B, int ldb, long sBz,
    void* __restrict__ Cv, int ldc, long sCz,
    int K, float scale,
    const float* __restrict__ bias0, const float* __restrict__ bias1,
    const float* __restrict__ bias2, float* __restrict__ rowsum)
{
  // 0..8191: sA (panel0 [128][32], panel1 [128][32]); 8192..16383: sB.
  // epilogue overlay: per-wave [64][72] scratch at wid*4608 (36864B total).
  __shared__ short lds[18432];
  short* sA = lds;
  short* sB = lds + 8192;

  const int tid  = threadIdx.x;
  const int lane = tid & 63;
  const int wid  = tid >> 6;
  const int z    = blockIdx.z;
  const long tileM = (long)blockIdx.y * 128;
  const long tileN = (long)blockIdx.x * 128;
  const short* Az = A + (long)z * sAz;
  const short* Bz = B + (long)z * sBz;

  // staging map: per k-tile (128 rows x 64 cols) = 1024 x 16B chunks.
  // chunk p = G*64+lane, G = g*4+wid: panel=p>>9, row=(p&511)>>2, col8=p&3.
  // g0: (r0, c0) panel0; g1: (+64 rows); g2: (+32 cols) panel1; g3: both.
  const int r0 = wid * 16 + (lane >> 2);
  const int c0 = (lane & 3) * 8;
  const short* gA0 = Az + (tileM + r0) * lda + c0;
  const short* gB0 = Bz + (tileN + r0) * ldb + c0;
  short* lA0 = sA + (wid * 64 + lane) * 8;
  short* lB0 = sB + (wid * 64 + lane) * 8;
  const long a64 = 64L * lda, b64 = 64L * ldb;

  const int fr = lane & 15, quad = lane >> 4;
  const int waveM = (wid >> 1) * 64, waveN = (wid & 1) * 64;

  f32x4 acc[4][4] = {};

  for (int kt = 0; kt < K; kt += 64) {
    __syncthreads();                 // prior readers done before overwrite
    gl16(gA0 + kt,             lA0);
    gl16(gA0 + kt + a64,       lA0 + 2048);
    gl16(gA0 + kt + 32,        lA0 + 4096);
    gl16(gA0 + kt + a64 + 32,  lA0 + 6144);
    gl16(gB0 + kt,             lB0);
    gl16(gB0 + kt + b64,       lB0 + 2048);
    gl16(gB0 + kt + 32,        lB0 + 4096);
    gl16(gB0 + kt + b64 + 32,  lB0 + 6144);
    __syncthreads();                 // loads landed in LDS

#pragma unroll
    for (int kk = 0; kk < 2; ++kk) {
      short8 af[4], bf[4];
#pragma unroll
      for (int i = 0; i < 4; ++i)
        af[i] = *(const short8*)&sA[kk * 4096 + (waveM + i * 16 + fr) * 32 + quad * 8];
#pragma unroll
      for (int j = 0; j < 4; ++j)
        bf[j] = *(const short8*)&sB[kk * 4096 + (waveN + j * 16 + fr) * 32 + quad * 8];
#pragma unroll
      for (int i = 0; i < 4; ++i)
#pragma unroll
        for (int j = 0; j < 4; ++j)
          acc[i][j] = __builtin_amdgcn_mfma_f32_16x16x32_bf16(af[i], bf[j],
                                                              acc[i][j], 0, 0, 0);
    }
  }

  // C/D layout per frag: row=(lane>>4)*4+r, col=lane&15 (m89/m91-verified).
  if (EPI == 1) {
    // exp2 in place, then per-row partial sums -> device atomics
#pragma unroll
    for (int i = 0; i < 4; ++i)
#pragma unroll
      for (int j = 0; j < 4; ++j)
#pragma unroll
        for (int r = 0; r < 4; ++r)
          acc[i][j][r] = exp2f(acc[i][j][r] * scale);
#pragma unroll
    for (int i = 0; i < 4; ++i)
#pragma unroll
      for (int r = 0; r < 4; ++r) {
        float s = acc[i][0][r] + acc[i][1][r] + acc[i][2][r] + acc[i][3][r];
        s += __shfl_xor(s, 1);
        s += __shfl_xor(s, 2);
        s += __shfl_xor(s, 4);
        s += __shfl_xor(s, 8);
        if (fr == 0)
          atomicAdd(&rowsum[(long)z * 2048 + tileM + waveM + i * 16 + quad * 4 + r], s);
      }
  }

  if (EPI <= 1) {
    // bf16 out via per-wave LDS transpose -> contiguous dwordx4 stores
    __syncthreads();                 // all frag reads done; reuse LDS
    short* scr = lds + wid * 4608;   // [64][72] (stride 144B: 16B-aligned rows)
    short* C = (short*)Cv + (long)z * sCz;
    const float* bias = (z == 0) ? bias0 : ((z == 1) ? bias1 : bias2);
#pragma unroll
    for (int j = 0; j < 4; ++j) {
      const float bv = (EPI == 0) ? bias[tileN + waveN + j * 16 + fr] : 0.0f;
#pragma unroll
      for (int i = 0; i < 4; ++i)
#pragma unroll
        for (int r = 0; r < 4; ++r)
          scr[(i * 16 + quad * 4 + r) * 72 + j * 16 + fr] =
              (short)f2bf(acc[i][j][r] + bv);
    }
    __syncthreads();                 // order ds_write -> ds_read (cheap, safe)
#pragma unroll
    for (int c = 0; c < 8; ++c) {
      const int row = c * 8 + (lane >> 3);
      const int col = (lane & 7) * 8;
      short8 v = *(const short8*)&scr[row * 72 + col];
      *(short8*)(C + (tileM + waveM + row) * ldc + tileN + waveN + col) = v;
    }
  } else {
    // EPI 2: fp32 out, normalized by rowsum
    float* C = (float*)Cv + (long)z * sCz;
#pragma unroll
    for (int i = 0; i < 4; ++i)
#pragma unroll
      for (int r = 0; r < 4; ++r) {
        const long gr = tileM + waveM + i * 16 + quad * 4 + r;
        const float rinv = 1.0f / rowsum[(long)z * 2048 + gr];
#pragma unroll
        for (int j = 0; j < 4; ++j)
          C[gr * ldc + tileN + waveN + j * 16 + fr] = acc[i][j][r] * rinv;
      }
  }
}

// fp32 -> bf16 elementwise, n = 8192*1024.
__global__ __launch_bounds__(256) void cvt_f32_to_bf16(
    const float4* __restrict__ x, ushort4* __restrict__ y)
{
  const long i = (long)blockIdx.x * 256 + threadIdx.x;
  float4 v = x[i];
  ushort4 o;
  o.x = f2bf(v.x); o.y = f2bf(v.y); o.z = f2bf(v.z); o.w = f2bf(v.w);
  y[i] = o;
}

// W [1024,1024] fp32 (d-major) -> WT bf16 (n-major), z selects q/k/v
__global__ __launch_bounds__(256) void transpose_cvt_w(
    const float* __restrict__ Wq, const float* __restrict__ Wk,
    const float* __restrict__ Wv, short* __restrict__ WT)
{
  __shared__ short tile[32][33];
  const int z = blockIdx.z;
  const float* W = (z == 0) ? Wq : ((z == 1) ? Wk : Wv);
  short* d = WT + (long)z * 1024 * 1024;
  const int n0 = blockIdx.x * 32, d0 = blockIdx.y * 32;
  const int tx = threadIdx.x & 31, ty = threadIdx.x >> 5;
#pragma unroll
  for (int p = 0; p < 4; ++p)
    tile[ty + p * 8][tx] = (short)f2bf(W[(long)(d0 + ty + p * 8) * 1024 + n0 + tx]);
  __syncthreads();
#pragma unroll
  for (int p = 0; p < 4; ++p)
    d[(long)(n0 + ty + p * 8) * 1024 + d0 + tx] = tile[tx][ty + p * 8];
}

// v [4][2048][1024] bf16 -> vT [4][1024][2048] bf16
__global__ __launch_bounds__(256) void transpose_bf16(
    const short* __restrict__ src, short* __restrict__ dst)
{
  __shared__ short tile[32][33];
  const int z = blockIdx.z;
  const int d0 = blockIdx.x * 32, t0 = blockIdx.y * 32;
  const int tx = threadIdx.x & 31, ty = threadIdx.x >> 5;
  const short* s = src + (long)z * 2048 * 1024;
  short* d = dst + (long)z * 1024 * 2048;
#pragma unroll
  for (int p = 0; p < 4; ++p)
    tile[ty + p * 8][tx] = s[(long)(t0 + ty + p * 8) * 1024 + d0 + tx];
  __syncthreads();
#pragma unroll
  for (int p = 0; p < 4; ++p)
    d[(long)(d0 + ty + p * 8) * 2048 + t0 + tx] = tile[tx][ty + p * 8];
}

extern "C" void kernel_launch(void* const* d_in, const int* in_sizes, int n_in,
                              void* d_out, int out_size, void* d_ws, size_t ws_size,
                              hipStream_t stream) {
  const float* x  = (const float*)d_in[0];
  const float* Wq = (const float*)d_in[1];
  const float* bq = (const float*)d_in[2];
  const float* Wk = (const float*)d_in[3];
  const float* bk = (const float*)d_in[4];
  const float* Wv = (const float*)d_in[5];
  const float* bv = (const float*)d_in[6];

  char* ws = (char*)d_ws;
  short* xb  = (short*)(ws);                  // 16 MB (reused as vT)
  short* wt  = (short*)(ws + 16777216);       // 6 MB
  short* qkv = (short*)(ws + 23068672);       // 48 MB: q|k|v [8192,1024] bf16
  short* Pp  = (short*)(ws + 73400320);       // 32 MB: [4][2048][2048] bf16
  float* rs  = (float*)(ws + 106954752);      // 32 KB: [4][2048] fp32
  short* vT  = xb;                            // [4][1024,2048]

  hipMemsetAsync(rs, 0, 4 * 2048 * sizeof(float), stream);
  // 1. x -> bf16
  cvt_f32_to_bf16<<<8192, 256, 0, stream>>>((const float4*)x, (ushort4*)xb);
  // 2. W^T -> bf16
  transpose_cvt_w<<<dim3(32, 32, 3), 256, 0, stream>>>(Wq, Wk, Wv, wt);
  // 3. q,k,v = x @ W + b   (bf16)
  gemm_bt<0><<<dim3(8, 64, 3), 256, 0, stream>>>(
      xb, 1024, 0L, wt, 1024, 1048576L, qkv, 1024, 8388608L,
      1024, 1.0f, bq, bk, bv, nullptr);
  // 4. vT per batch
  transpose_bf16<<<dim3(32, 64, 4), 256, 0, stream>>>(qkv + 2L * 8388608, vT);
  // 5. P' = exp2(q@k^T * scale*log2e), bf16 + rowsum atomics
  gemm_bt<1><<<dim3(16, 16, 4), 256, 0, stream>>>(
      qkv, 1024, 2097152L, qkv + 8388608, 1024, 2097152L, Pp, 2048, 4194304L,
      1024, 0.03125f * 1.44269504088896f, nullptr, nullptr, nullptr, rs);
  // 6. out = (P' @ vT^T) / rowsum  (fp32 -> d_out)
  gemm_bt<2><<<dim3(8, 16, 4), 256, 0, stream>>>(
      Pp, 2048, 4194304L, vT, 2048, 2097152L, d_out, 1024, 2097152L,
      2048, 1.0f, nullptr, nullptr, nullptr, rs);
}

// Round 3
// 275.022 us; speedup vs baseline: 1.2043x; 1.0879x over previous
//
#include <hip/hip_runtime.h>
#include <hip/hip_bf16.h>
#include <stdint.h>

// ---------------------------------------------------------------------------
// Single-head self-attention, B=4, S=2048, D=1024, fp32 in/out.
// Round 3: double-buffered BK=32 staging (one barrier per k-iter; gl16 for
// tile t+1 issued while computing tile t), merged prep kernel, distinct GEMM
// names. LDS stays 36.9KB (staging 2x16KB under the epilogue overlay).
// Pipeline:
//   1. prep: xb=bf16(x); wt=bf16(W^T) q,k,v; rowsum=0
//   2. qkv  = xb @ wt^T + bias    (EPI0, bf16) [3][8192,1024]
//   3. vT   = transpose(v) per batch           [4][1024,2048]
//   4. P'   = exp2(q@k^T * s*log2e) (EPI1, bf16) + rowsum atomics
//   5. out  = (P' @ vT^T) / rowsum (EPI2, fp32 -> d_out)
// ---------------------------------------------------------------------------

typedef __attribute__((ext_vector_type(8))) short short8;   // 8 bf16 = 4 VGPR
typedef __attribute__((ext_vector_type(4))) float f32x4;    // MFMA C/D

__device__ __forceinline__ unsigned short f2bf(float f) {
  union { float f; uint32_t u; } c; c.f = f;
  uint32_t u = c.u;
  u += 0x7FFFu + ((u >> 16) & 1u);   // RNE
  return (unsigned short)(u >> 16);
}

// async global->LDS, 16B/lane; LDS dest is wave-uniform base + lane*16.
__device__ __forceinline__ void gl16(const void* g, void* l) {
  __builtin_amdgcn_global_load_lds(
      (const __attribute__((address_space(1))) unsigned int*)g,
      (__attribute__((address_space(3))) unsigned int*)l, 16, 0, 0);
}

// C = A @ B^T. A: [M,K] bf16 (lda), B: [N,K] bf16 (ldb). BK=32, double-buffer.
// EPI 0: C bf16, += bias[col] (selected by z).
// EPI 1: C bf16 = exp2(acc*scale); fp32 rowsum atomics (softmax numerator).
// EPI 2: C fp32 = acc / rowsum[row].
// Grid (N/128, M/128, Z), block 256 = 4 waves (2x2 of 64x64).
template <int EPI>
__device__ __forceinline__ void gemm_body(
    const short* __restrict__ A, int lda, long sAz,
    const short* __restrict__ B, int ldb, long sBz,
    void* __restrict__ Cv, int ldc, long sCz,
    int K, float scale,
    const float* __restrict__ bias0, const float* __restrict__ bias1,
    const float* __restrict__ bias2, float* __restrict__ rowsum)
{
  // buffers: buf b at lds + b*8192 shorts (sA 4096 | sB 4096), b in {0,1}.
  // epilogue overlay: per-wave [64][72] shorts at wid*4608 (36864B total).
  __shared__ short lds[18432];

  const int tid  = threadIdx.x;
  const int lane = tid & 63;
  const int wid  = tid >> 6;
  const int z    = blockIdx.z;
  const long tileM = (long)blockIdx.y * 128;
  const long tileN = (long)blockIdx.x * 128;
  const short* Az = A + (long)z * sAz;
  const short* Bz = B + (long)z * sBz;

  // staging: per 128x32 tile = 512 x 16B chunks per matrix; chunk c:
  // row=c>>2, col8=c&3, lds offset c*8 shorts. c0=tid covers rows 0..63,
  // c1=256+tid rows 64..127. gl16 lane-contiguity: c = G*64+lane, G uniform.
  const int c0 = tid, c1 = 256 + tid;
  const short* gA0 = Az + (tileM + (c0 >> 2)) * lda + (c0 & 3) * 8;
  const short* gA1 = Az + (tileM + (c1 >> 2)) * lda + (c1 & 3) * 8;
  const short* gB0 = Bz + (tileN + (c0 >> 2)) * ldb + (c0 & 3) * 8;
  const short* gB1 = Bz + (tileN + (c1 >> 2)) * ldb + (c1 & 3) * 8;

  const int fr = lane & 15, quad = lane >> 4;
  const int waveM = (wid >> 1) * 64, waveN = (wid & 1) * 64;

  f32x4 acc[4][4] = {};

  const int T = K >> 5;   // k-tiles of 32

  // prologue: issue tile 0 into buf 0
  {
    short* base = lds;
    gl16(gA0, base + c0 * 8);
    gl16(gA1, base + c1 * 8);
    gl16(gB0, base + 4096 + c0 * 8);
    gl16(gB1, base + 4096 + c1 * 8);
  }

  for (int t = 0; t < T; ++t) {
    __syncthreads();   // drains (vmcnt0) tile t's loads; buf (t+1)&1 readers done
    if (t + 1 < T) {
      const int kt = (t + 1) << 5;
      short* base = lds + ((t + 1) & 1) * 8192;
      gl16(gA0 + kt, base + c0 * 8);
      gl16(gA1 + kt, base + c1 * 8);
      gl16(gB0 + kt, base + 4096 + c0 * 8);
      gl16(gB1 + kt, base + 4096 + c1 * 8);
    }
    const short* sA = lds + (t & 1) * 8192;
    const short* sB = sA + 4096;
    short8 af[4], bf[4];
#pragma unroll
    for (int i = 0; i < 4; ++i)
      af[i] = *(const short8*)&sA[(waveM + i * 16 + fr) * 32 + quad * 8];
#pragma unroll
    for (int j = 0; j < 4; ++j)
      bf[j] = *(const short8*)&sB[(waveN + j * 16 + fr) * 32 + quad * 8];
#pragma unroll
    for (int i = 0; i < 4; ++i)
#pragma unroll
      for (int j = 0; j < 4; ++j)
        acc[i][j] = __builtin_amdgcn_mfma_f32_16x16x32_bf16(af[i], bf[j],
                                                            acc[i][j], 0, 0, 0);
  }

  // C/D layout per frag: row=(lane>>4)*4+r, col=lane&15 (m89/m91-verified).
  if (EPI == 1) {
#pragma unroll
    for (int i = 0; i < 4; ++i)
#pragma unroll
      for (int j = 0; j < 4; ++j)
#pragma unroll
        for (int r = 0; r < 4; ++r)
          acc[i][j][r] = exp2f(acc[i][j][r] * scale);
#pragma unroll
    for (int i = 0; i < 4; ++i)
#pragma unroll
      for (int r = 0; r < 4; ++r) {
        float s = acc[i][0][r] + acc[i][1][r] + acc[i][2][r] + acc[i][3][r];
        s += __shfl_xor(s, 1);
        s += __shfl_xor(s, 2);
        s += __shfl_xor(s, 4);
        s += __shfl_xor(s, 8);
        if (fr == 0)
          atomicAdd(&rowsum[(long)z * 2048 + tileM + waveM + i * 16 + quad * 4 + r], s);
      }
  }

  if (EPI <= 1) {
    // bf16 out via per-wave LDS transpose -> contiguous dwordx4 stores.
    __syncthreads();                 // other waves' frag reads done; reuse LDS
    short* scr = lds + wid * 4608;   // [64][72] per wave (rows 16B-aligned)
    short* C = (short*)Cv + (long)z * sCz;
    const float* bias = (z == 0) ? bias0 : ((z == 1) ? bias1 : bias2);
#pragma unroll
    for (int j = 0; j < 4; ++j) {
      const float bv = (EPI == 0) ? bias[tileN + waveN + j * 16 + fr] : 0.0f;
#pragma unroll
      for (int i = 0; i < 4; ++i)
#pragma unroll
        for (int r = 0; r < 4; ++r)
          scr[(i * 16 + quad * 4 + r) * 72 + j * 16 + fr] =
              (short)f2bf(acc[i][j][r] + bv);
    }
    // per-wave scratch: ds_write->ds_read ordering is via lgkmcnt (no barrier)
#pragma unroll
    for (int c = 0; c < 8; ++c) {
      const int row = c * 8 + (lane >> 3);
      const int col = (lane & 7) * 8;
      short8 v = *(const short8*)&scr[row * 72 + col];
      *(short8*)(C + (tileM + waveM + row) * ldc + tileN + waveN + col) = v;
    }
  } else {
    // EPI 2: fp32 out, normalized by rowsum
    float* C = (float*)Cv + (long)z * sCz;
#pragma unroll
    for (int i = 0; i < 4; ++i)
#pragma unroll
      for (int r = 0; r < 4; ++r) {
        const long gr = tileM + waveM + i * 16 + quad * 4 + r;
        const float rinv = 1.0f / rowsum[(long)z * 2048 + gr];
#pragma unroll
        for (int j = 0; j < 4; ++j)
          C[gr * ldc + tileN + waveN + j * 16 + fr] = acc[i][j][r] * rinv;
      }
  }
}

__global__ __launch_bounds__(256) void gemm_qkv(
    const short* A, int lda, long sAz, const short* B, int ldb, long sBz,
    void* Cv, int ldc, long sCz, int K, float scale,
    const float* b0, const float* b1, const float* b2, float* rs) {
  gemm_body<0>(A, lda, sAz, B, ldb, sBz, Cv, ldc, sCz, K, scale, b0, b1, b2, rs);
}
__global__ __launch_bounds__(256) void gemm_score(
    const short* A, int lda, long sAz, const short* B, int ldb, long sBz,
    void* Cv, int ldc, long sCz, int K, float scale,
    const float* b0, const float* b1, const float* b2, float* rs) {
  gemm_body<1>(A, lda, sAz, B, ldb, sBz, Cv, ldc, sCz, K, scale, b0, b1, b2, rs);
}
__global__ __launch_bounds__(256) void gemm_pv(
    const short* A, int lda, long sAz, const short* B, int ldb, long sBz,
    void* Cv, int ldc, long sCz, int K, float scale,
    const float* b0, const float* b1, const float* b2, float* rs) {
  gemm_body<2>(A, lda, sAz, B, ldb, sBz, Cv, ldc, sCz, K, scale, b0, b1, b2, rs);
}

// prep: blocks [0,8192) cvt x -> bf16; [8192,11264) W^T -> bf16; 11264 zero rs
__global__ __launch_bounds__(256) void prep(
    const float4* __restrict__ x, ushort4* __restrict__ xb,
    const float* __restrict__ Wq, const float* __restrict__ Wk,
    const float* __restrict__ Wv, short* __restrict__ WT,
    float* __restrict__ rs)
{
  __shared__ short tile[32][33];
  const int b = blockIdx.x;
  if (b < 8192) {
    const long i = (long)b * 256 + threadIdx.x;
    float4 v = x[i];
    ushort4 o;
    o.x = f2bf(v.x); o.y = f2bf(v.y); o.z = f2bf(v.z); o.w = f2bf(v.w);
    xb[i] = o;
  } else if (b < 11264) {
    const int idx = b - 8192;
    const int z = idx >> 10, rem = idx & 1023;
    const float* W = (z == 0) ? Wq : ((z == 1) ? Wk : Wv);
    short* d = WT + (long)z * 1024 * 1024;
    const int n0 = (rem & 31) * 32, d0 = (rem >> 5) * 32;
    const int tx = threadIdx.x & 31, ty = threadIdx.x >> 5;
#pragma unroll
    for (int p = 0; p < 4; ++p)
      tile[ty + p * 8][tx] = (short)f2bf(W[(long)(d0 + ty + p * 8) * 1024 + n0 + tx]);
    __syncthreads();
#pragma unroll
    for (int p = 0; p < 4; ++p)
      d[(long)(n0 + ty + p * 8) * 1024 + d0 + tx] = tile[tx][ty + p * 8];
  } else {
#pragma unroll
    for (int p = 0; p < 32; ++p)
      rs[p * 256 + threadIdx.x] = 0.0f;
  }
}

// v [4][2048][1024] bf16 -> vT [4][1024][2048] bf16
__global__ __launch_bounds__(256) void transpose_bf16(
    const short* __restrict__ src, short* __restrict__ dst)
{
  __shared__ short tile[32][33];
  const int z = blockIdx.z;
  const int d0 = blockIdx.x * 32, t0 = blockIdx.y * 32;
  const int tx = threadIdx.x & 31, ty = threadIdx.x >> 5;
  const short* s = src + (long)z * 2048 * 1024;
  short* d = dst + (long)z * 1024 * 2048;
#pragma unroll
  for (int p = 0; p < 4; ++p)
    tile[ty + p * 8][tx] = s[(long)(t0 + ty + p * 8) * 1024 + d0 + tx];
  __syncthreads();
#pragma unroll
  for (int p = 0; p < 4; ++p)
    d[(long)(d0 + ty + p * 8) * 2048 + t0 + tx] = tile[tx][ty + p * 8];
}

extern "C" void kernel_launch(void* const* d_in, const int* in_sizes, int n_in,
                              void* d_out, int out_size, void* d_ws, size_t ws_size,
                              hipStream_t stream) {
  const float* x  = (const float*)d_in[0];
  const float* Wq = (const float*)d_in[1];
  const float* bq = (const float*)d_in[2];
  const float* Wk = (const float*)d_in[3];
  const float* bk = (const float*)d_in[4];
  const float* Wv = (const float*)d_in[5];
  const float* bv = (const float*)d_in[6];

  char* ws = (char*)d_ws;
  short* xb  = (short*)(ws);                  // 16 MB (reused as vT)
  short* wt  = (short*)(ws + 16777216);       // 6 MB
  short* qkv = (short*)(ws + 23068672);       // 48 MB: q|k|v [8192,1024] bf16
  short* Pp  = (short*)(ws + 73400320);       // 32 MB: [4][2048][2048] bf16
  float* rs  = (float*)(ws + 106954752);      // 32 KB: [4][2048] fp32
  short* vT  = xb;                            // [4][1024,2048]

  // 1. prep: xb, wt, rowsum=0
  prep<<<11265, 256, 0, stream>>>((const float4*)x, (ushort4*)xb,
                                  Wq, Wk, Wv, wt, rs);
  // 2. q,k,v = x @ W + b   (bf16)
  gemm_qkv<<<dim3(8, 64, 3), 256, 0, stream>>>(
      xb, 1024, 0L, wt, 1024, 1048576L, qkv, 1024, 8388608L,
      1024, 1.0f, bq, bk, bv, nullptr);
  // 3. vT per batch
  transpose_bf16<<<dim3(32, 64, 4), 256, 0, stream>>>(qkv + 2L * 8388608, vT);
  // 4. P' = exp2(q@k^T * scale*log2e), bf16 + rowsum atomics
  gemm_score<<<dim3(16, 16, 4), 256, 0, stream>>>(
      qkv, 1024, 2097152L, qkv + 8388608, 1024, 2097152L, Pp, 2048, 4194304L,
      1024, 0.03125f * 1.44269504088896f, nullptr, nullptr, nullptr, rs);
  // 5. out = (P' @ vT^T) / rowsum  (fp32 -> d_out)
  gemm_pv<<<dim3(8, 16, 4), 256, 0, stream>>>(
      Pp, 2048, 4194304L, vT, 2048, 2097152L, d_out, 1024, 2097152L,
      2048, 1.0f, nullptr, nullptr, nullptr, rs);
}

// Round 4
// 265.813 us; speedup vs baseline: 1.2460x; 1.0346x over previous
//
#include <hip/hip_runtime.h>
#include <hip/hip_bf16.h>
#include <stdint.h>

// ---------------------------------------------------------------------------
// Single-head self-attention, B=4, S=2048, D=1024, fp32 in/out.
// Round 4: XCD-aligned supertile swizzles (xcd = blockIdx%8 assumption) to cut
// per-XCD L2 fill for all 3 GEMMs; v-transpose fused into qkv epilogue
// (z==2 writes vT directly via transposed LDS scratch). 4 dispatches total.
// Pipeline:
//   1. prep: xb=bf16(x); wt=bf16(W^T) q,k,v; rowsum=0
//   2. MODE0: q,k = x@W+b (bf16); v -> written TRANSPOSED as vT [4][1024][2048]
//   3. MODE1: P' = exp2(q@k^T * s*log2e) (bf16) + rowsum atomics
//   4. MODE2: out = (P' @ vT^T) / rowsum (fp32 -> d_out)
// ---------------------------------------------------------------------------

typedef __attribute__((ext_vector_type(8))) short short8;   // 8 bf16 = 4 VGPR
typedef __attribute__((ext_vector_type(4))) float f32x4;    // MFMA C/D

__device__ __forceinline__ unsigned short f2bf(float f) {
  union { float f; uint32_t u; } c; c.f = f;
  uint32_t u = c.u;
  u += 0x7FFFu + ((u >> 16) & 1u);   // RNE
  return (unsigned short)(u >> 16);
}

// async global->LDS, 16B/lane; LDS dest is wave-uniform base + lane*16.
__device__ __forceinline__ void gl16(const void* g, void* l) {
  __builtin_amdgcn_global_load_lds(
      (const __attribute__((address_space(1))) unsigned int*)g,
      (__attribute__((address_space(3))) unsigned int*)l, 16, 0, 0);
}

// C = A @ B^T, 128x128 tile, BK=32 double-buffered, 4 waves (2x2 of 64x64).
// MODE 0 (qkv): z in {0,1,2}; K=1024; C bf16 += bias[col]; z==2 writes vT.
// MODE 1 (score): K=1024; C bf16 = exp2(acc*scale); rowsum atomics.
// MODE 2 (pv): K=2048; C fp32 = acc / rowsum[row].
template <int MODE>
__global__ __launch_bounds__(256) void gemm(
    const short* __restrict__ A, const short* __restrict__ B,
    void* __restrict__ Cv, short* __restrict__ vT, float scale,
    const float* __restrict__ bias0, const float* __restrict__ bias1,
    const float* __restrict__ bias2, float* __restrict__ rowsum)
{
  constexpr int  LDA = (MODE == 2) ? 2048 : 1024;
  constexpr int  LDB = (MODE == 2) ? 2048 : 1024;
  constexpr int  LDC = (MODE == 0) ? 1024 : ((MODE == 1) ? 2048 : 1024);
  constexpr long SAZ = (MODE == 0) ? 0L : ((MODE == 1) ? 2097152L : 4194304L);
  constexpr long SBZ = (MODE == 0) ? 1048576L : 2097152L;
  constexpr long SCZ = (MODE == 0) ? 8388608L : ((MODE == 1) ? 4194304L : 2097152L);
  constexpr int  T   = (MODE == 2) ? 64 : 32;   // k-tiles of 32

  // XCD-aligned supertile decode (xcd presumed = blockIdx % 8)
  int z, tm, tn;
  {
    const int b = blockIdx.x;
    if (MODE == 0) {
      // 1536 blocks: xcd owns tileM rows xcd*8..xcd*8+7 for ALL z (A shared)
      const int xcd = b & 7, r = b >> 3;
      z = r >> 6;                       // 0..2
      const int mem = r & 63;           // 8 rows x 8 cols
      tm = xcd * 8 + (mem >> 3);        // 0..63
      tn = mem & 7;                     // 0..7
    } else if (MODE == 1) {
      // 1024 blocks: per batch 16 supertiles (4x4 blocks); xcd gets s, s+8
      const int xcd = b & 7, r = b >> 3;
      z = r >> 5;                       // 0..3
      const int pair = (r >> 4) & 1, mem = r & 15;
      const int s = pair * 8 + xcd;     // 0..15
      tm = (s >> 2) * 4 + (mem >> 2);   // 0..15
      tn = (s & 3) * 4 + (mem & 3);     // 0..15
    } else {
      // 512 blocks: per batch 8 supertiles (4x4); one per xcd per batch
      const int s = b & 7, r = b >> 3;
      z = r >> 4;                       // 0..3
      const int mem = r & 15;
      tm = (s >> 1) * 4 + (mem >> 2);   // 0..15
      tn = (s & 1) * 4 + (mem & 3);     // 0..7
    }
  }

  // staging: buf b at lds + b*8192 shorts (sA 4096 | sB 4096).
  // epilogue overlay: per-wave [64][72] shorts at wid*4608 (36864B total).
  __shared__ short lds[18432];

  const int tid  = threadIdx.x;
  const int lane = tid & 63;
  const int wid  = tid >> 6;
  const long tileM = (long)tm * 128;
  const long tileN = (long)tn * 128;
  const short* Az = A + (long)z * SAZ;
  const short* Bz = B + (long)z * SBZ;

  // per 128x32 tile: 512 x 16B chunks per matrix; chunk c: row=c>>2, col8=c&3
  const int c0 = tid, c1 = 256 + tid;
  const short* gA0 = Az + (tileM + (c0 >> 2)) * LDA + (c0 & 3) * 8;
  const short* gA1 = Az + (tileM + (c1 >> 2)) * LDA + (c1 & 3) * 8;
  const short* gB0 = Bz + (tileN + (c0 >> 2)) * LDB + (c0 & 3) * 8;
  const short* gB1 = Bz + (tileN + (c1 >> 2)) * LDB + (c1 & 3) * 8;

  const int fr = lane & 15, quad = lane >> 4;
  const int waveM = (wid >> 1) * 64, waveN = (wid & 1) * 64;

  f32x4 acc[4][4] = {};

  // prologue: tile 0 -> buf 0
  {
    short* base = lds;
    gl16(gA0, base + c0 * 8);
    gl16(gA1, base + c1 * 8);
    gl16(gB0, base + 4096 + c0 * 8);
    gl16(gB1, base + 4096 + c1 * 8);
  }

  for (int t = 0; t < T; ++t) {
    __syncthreads();   // drains tile t's loads; buf (t+1)&1 readers done
    if (t + 1 < T) {
      const int kt = (t + 1) << 5;
      short* base = lds + ((t + 1) & 1) * 8192;
      gl16(gA0 + kt, base + c0 * 8);
      gl16(gA1 + kt, base + c1 * 8);
      gl16(gB0 + kt, base + 4096 + c0 * 8);
      gl16(gB1 + kt, base + 4096 + c1 * 8);
    }
    const short* sA = lds + (t & 1) * 8192;
    const short* sB = sA + 4096;
    short8 af[4], bf[4];
#pragma unroll
    for (int i = 0; i < 4; ++i)
      af[i] = *(const short8*)&sA[(waveM + i * 16 + fr) * 32 + quad * 8];
#pragma unroll
    for (int j = 0; j < 4; ++j)
      bf[j] = *(const short8*)&sB[(waveN + j * 16 + fr) * 32 + quad * 8];
#pragma unroll
    for (int i = 0; i < 4; ++i)
#pragma unroll
      for (int j = 0; j < 4; ++j)
        acc[i][j] = __builtin_amdgcn_mfma_f32_16x16x32_bf16(af[i], bf[j],
                                                            acc[i][j], 0, 0, 0);
  }

  // C/D layout per frag: row=(lane>>4)*4+r, col=lane&15 (m89/m91-verified).
  if (MODE == 1) {
#pragma unroll
    for (int i = 0; i < 4; ++i)
#pragma unroll
      for (int j = 0; j < 4; ++j)
#pragma unroll
        for (int r = 0; r < 4; ++r)
          acc[i][j][r] = exp2f(acc[i][j][r] * scale);
#pragma unroll
    for (int i = 0; i < 4; ++i)
#pragma unroll
      for (int r = 0; r < 4; ++r) {
        float s = acc[i][0][r] + acc[i][1][r] + acc[i][2][r] + acc[i][3][r];
        s += __shfl_xor(s, 1);
        s += __shfl_xor(s, 2);
        s += __shfl_xor(s, 4);
        s += __shfl_xor(s, 8);
        if (fr == 0)
          atomicAdd(&rowsum[(long)z * 2048 + tileM + waveM + i * 16 + quad * 4 + r], s);
      }
  }

  if (MODE == 0 && z == 2) {
    // v-tile: add bias, write TRANSPOSED scratch [d][t], store to vT[b][d][t]
    __syncthreads();                 // other waves' staging reads done
    short* scr = lds + wid * 4608;   // [64][72]
#pragma unroll
    for (int j = 0; j < 4; ++j) {
      const float bv = bias2[tileN + waveN + j * 16 + fr];
#pragma unroll
      for (int i = 0; i < 4; ++i)
#pragma unroll
        for (int r = 0; r < 4; ++r)
          scr[(j * 16 + fr) * 72 + i * 16 + quad * 4 + r] =
              (short)f2bf(acc[i][j][r] + bv);
    }
    const int gb = tm >> 4;                    // batch
    const long t0 = (long)(tm & 15) * 128 + waveM;
#pragma unroll
    for (int c = 0; c < 8; ++c) {
      const int rr = c * 8 + (lane >> 3);      // d within wave tile
      const int cc = (lane & 7) * 8;           // t within wave tile
      short8 v = *(const short8*)&scr[rr * 72 + cc];
      const long gd = tileN + waveN + rr;
      *(short8*)(vT + ((long)gb << 21) + gd * 2048 + t0 + cc) = v;
    }
  } else if (MODE <= 1) {
    // bf16 out via per-wave LDS transpose -> contiguous dwordx4 stores
    __syncthreads();                 // other waves' staging reads done
    short* scr = lds + wid * 4608;   // [64][72]
    short* C = (short*)Cv + (long)z * SCZ;
    const float* bias = (z == 0) ? bias0 : bias1;
#pragma unroll
    for (int j = 0; j < 4; ++j) {
      const float bv = (MODE == 0) ? bias[tileN + waveN + j * 16 + fr] : 0.0f;
#pragma unroll
      for (int i = 0; i < 4; ++i)
#pragma unroll
        for (int r = 0; r < 4; ++r)
          scr[(i * 16 + quad * 4 + r) * 72 + j * 16 + fr] =
              (short)f2bf(acc[i][j][r] + bv);
    }
    // per-wave scratch: ds_write->ds_read ordering via lgkmcnt (no barrier)
#pragma unroll
    for (int c = 0; c < 8; ++c) {
      const int row = c * 8 + (lane >> 3);
      const int col = (lane & 7) * 8;
      short8 v = *(const short8*)&scr[row * 72 + col];
      *(short8*)(C + (tileM + waveM + row) * LDC + tileN + waveN + col) = v;
    }
  } else {
    // MODE 2: fp32 out, normalized by rowsum
    float* C = (float*)Cv + (long)z * SCZ;
#pragma unroll
    for (int i = 0; i < 4; ++i)
#pragma unroll
      for (int r = 0; r < 4; ++r) {
        const long gr = tileM + waveM + i * 16 + quad * 4 + r;
        const float rinv = 1.0f / rowsum[(long)z * 2048 + gr];
#pragma unroll
        for (int j = 0; j < 4; ++j)
          C[gr * LDC + tileN + waveN + j * 16 + fr] = acc[i][j][r] * rinv;
      }
  }
}

// prep: blocks [0,8192) cvt x -> bf16; [8192,11264) W^T -> bf16; 11264 zero rs
__global__ __launch_bounds__(256) void prep(
    const float4* __restrict__ x, ushort4* __restrict__ xb,
    const float* __restrict__ Wq, const float* __restrict__ Wk,
    const float* __restrict__ Wv, short* __restrict__ WT,
    float* __restrict__ rs)
{
  __shared__ short tile[32][33];
  const int b = blockIdx.x;
  if (b < 8192) {
    const long i = (long)b * 256 + threadIdx.x;
    float4 v = x[i];
    ushort4 o;
    o.x = f2bf(v.x); o.y = f2bf(v.y); o.z = f2bf(v.z); o.w = f2bf(v.w);
    xb[i] = o;
  } else if (b < 11264) {
    const int idx = b - 8192;
    const int z = idx >> 10, rem = idx & 1023;
    const float* W = (z == 0) ? Wq : ((z == 1) ? Wk : Wv);
    short* d = WT + (long)z * 1024 * 1024;
    const int n0 = (rem & 31) * 32, d0 = (rem >> 5) * 32;
    const int tx = threadIdx.x & 31, ty = threadIdx.x >> 5;
#pragma unroll
    for (int p = 0; p < 4; ++p)
      tile[ty + p * 8][tx] = (short)f2bf(W[(long)(d0 + ty + p * 8) * 1024 + n0 + tx]);
    __syncthreads();
#pragma unroll
    for (int p = 0; p < 4; ++p)
      d[(long)(n0 + ty + p * 8) * 1024 + d0 + tx] = tile[tx][ty + p * 8];
  } else {
#pragma unroll
    for (int p = 0; p < 32; ++p)
      rs[p * 256 + threadIdx.x] = 0.0f;
  }
}

extern "C" void kernel_launch(void* const* d_in, const int* in_sizes, int n_in,
                              void* d_out, int out_size, void* d_ws, size_t ws_size,
                              hipStream_t stream) {
  const float* x  = (const float*)d_in[0];
  const float* Wq = (const float*)d_in[1];
  const float* bq = (const float*)d_in[2];
  const float* Wk = (const float*)d_in[3];
  const float* bk = (const float*)d_in[4];
  const float* Wv = (const float*)d_in[5];
  const float* bv = (const float*)d_in[6];

  char* ws = (char*)d_ws;
  short* xb  = (short*)(ws);                  // 16 MB
  short* wt  = (short*)(ws + 16777216);       // 6 MB
  short* qkv = (short*)(ws + 23068672);       // 48 MB: q | k | vT
  short* Pp  = (short*)(ws + 73400320);       // 32 MB: [4][2048][2048] bf16
  float* rs  = (float*)(ws + 106954752);      // 32 KB: [4][2048] fp32
  short* vT  = qkv + 2L * 8388608;            // [4][1024][2048] bf16

  // 1. prep: xb, wt, rowsum=0
  prep<<<11265, 256, 0, stream>>>((const float4*)x, (ushort4*)xb,
                                  Wq, Wk, Wv, wt, rs);
  // 2. q,k = x@W+b (bf16); v written transposed into vT
  gemm<0><<<1536, 256, 0, stream>>>(xb, wt, qkv, vT, 1.0f, bq, bk, bv, nullptr);
  // 3. P' = exp2(q@k^T * scale*log2e), bf16 + rowsum atomics
  gemm<1><<<1024, 256, 0, stream>>>(qkv, qkv + 8388608, Pp, nullptr,
                                    0.03125f * 1.44269504088896f,
                                    nullptr, nullptr, nullptr, rs);
  // 4. out = (P' @ vT^T) / rowsum  (fp32 -> d_out)
  gemm<2><<<512, 256, 0, stream>>>(Pp, vT, d_out, nullptr, 1.0f,
                                   nullptr, nullptr, nullptr, rs);
}